// Round 8
// baseline (526.187 us; speedup 1.0000x reference)
//
#include <hip/hip_runtime.h>
#include <math.h>

#define NP   100000
#define EDG  1600000
#define NK   15
#define SIGK 0.04f
#define SCH  2048
#define SNB  49            // ceil(NP/SCH)
#define MAXE 256           // max ACTIVE edges per 16-query block (Poisson ~125, >10 sigma)
#define AGP  968           // agg pitch in bf16 (960 + 8 pad)
#define ISTR 20            // inflF row stride in floats (bank spread: 20 mod 32 cycles per 8 rows)

typedef __bf16 v8bf __attribute__((ext_vector_type(8)));
typedef __bf16 bf4  __attribute__((ext_vector_type(4)));
typedef float  v4f  __attribute__((ext_vector_type(4)));

__device__ __forceinline__ float lk(float v) { return v >= 0.f ? v : 0.1f * v; }
__device__ __forceinline__ float bf2f(__bf16 b) { return (float)b; }

// ---------------------------------------------------------------------------
// MFMA GEMM: Out[n x Ntot] = X[n x KIN] @ W, W preshuffled bf16 B-frags.
// Block 256 thr = 4 waves; tile 128 rows x NB cols. Column stats fused.
// Stats -> replicated accumulators (32 replicas) to avoid hot-line atomics.
// ---------------------------------------------------------------------------
template <int KIN, int NB, bool TRANS, bool OUTBF>
__global__ __launch_bounds__(256) void mgemm_k(const float* __restrict__ X,
                                               const __bf16* __restrict__ Wp,
                                               void* __restrict__ Out, int n, int Ntot,
                                               const float* __restrict__ ta,
                                               const float* __restrict__ tb,
                                               float* __restrict__ osum,
                                               float* __restrict__ osq) {
  constexpr int PITCH = KIN + 8;
  constexpr int NT = NB / 16;
  __shared__ __bf16 al[128 * PITCH];
  __shared__ float red[2][NB][4];
  const int tid = threadIdx.x;
  const int r0 = blockIdx.x << 7;
  const int nb0 = blockIdx.y * NB;

  constexpr int QKS = (KIN == 128) ? 5 : 4;  // log2(KIN/4)
  for (int idx = tid; idx < (128 << QKS); idx += 256) {
    const int r = idx >> QKS, q = (idx & ((1 << QKS) - 1)) << 2;
    const int row = r0 + r;
    float4 v = make_float4(0.f, 0.f, 0.f, 0.f);
    if (row < n) {
      v = *(const float4*)&X[(size_t)row * KIN + q];
      if (TRANS) {
        v.x = lk(ta[q + 0] * v.x + tb[q + 0]);
        v.y = lk(ta[q + 1] * v.y + tb[q + 1]);
        v.z = lk(ta[q + 2] * v.z + tb[q + 2]);
        v.w = lk(ta[q + 3] * v.w + tb[q + 3]);
      }
    }
    bf4 o;
    o[0] = (__bf16)v.x; o[1] = (__bf16)v.y; o[2] = (__bf16)v.z; o[3] = (__bf16)v.w;
    *(bf4*)&al[r * PITCH + q] = o;
  }
  __syncthreads();

  const int wv = tid >> 6, lane = tid & 63;
  const int mr = lane & 15, quad = lane >> 4;
  const int ntg0 = nb0 >> 4;
  const int NTG = Ntot >> 4;
  v4f acc[2][NT];
#pragma unroll
  for (int a = 0; a < 2; ++a)
#pragma unroll
    for (int b = 0; b < NT; ++b) acc[a][b] = (v4f){0.f, 0.f, 0.f, 0.f};

#pragma unroll
  for (int ks = 0; ks < KIN / 32; ++ks) {
    v8bf bf[NT];
#pragma unroll
    for (int nt = 0; nt < NT; ++nt)
      bf[nt] = ((const v8bf*)Wp)[((size_t)ks * NTG + ntg0 + nt) * 64 + lane];
#pragma unroll
    for (int mt = 0; mt < 2; ++mt) {
      const int row = (wv << 5) + (mt << 4) + mr;
      const v8bf av = *(const v8bf*)&al[row * PITCH + (ks << 5) + (quad << 3)];
#pragma unroll
      for (int nt = 0; nt < NT; ++nt)
        acc[mt][nt] = __builtin_amdgcn_mfma_f32_16x16x32_bf16(av, bf[nt], acc[mt][nt], 0, 0, 0);
    }
  }

  float csum[NT], csq[NT];
#pragma unroll
  for (int nt = 0; nt < NT; ++nt) { csum[nt] = 0.f; csq[nt] = 0.f; }
#pragma unroll
  for (int mt = 0; mt < 2; ++mt)
#pragma unroll
    for (int nt = 0; nt < NT; ++nt)
#pragma unroll
      for (int r = 0; r < 4; ++r) {
        const float v = acc[mt][nt][r];
        const int row = r0 + (wv << 5) + (mt << 4) + (quad << 2) + r;
        if (row < n) {
          const size_t o = (size_t)row * Ntot + nb0 + (nt << 4) + mr;
          if (OUTBF) ((__bf16*)Out)[o] = (__bf16)v;
          else       ((float*)Out)[o] = v;
        }
        csum[nt] += v;
        csq[nt] += v * v;
      }
#pragma unroll
  for (int nt = 0; nt < NT; ++nt) {
    float s = csum[nt], q = csq[nt];
    s += __shfl_down(s, 32); s += __shfl_down(s, 16);
    q += __shfl_down(q, 32); q += __shfl_down(q, 16);
    if (quad == 0) { red[0][(nt << 4) + mr][wv] = s; red[1][(nt << 4) + mr][wv] = q; }
  }
  __syncthreads();
  if (tid < NB) {
    const float s = red[0][tid][0] + red[0][tid][1] + red[0][tid][2] + red[0][tid][3];
    const float q = red[1][tid][0] + red[1][tid][1] + red[1][tid][2] + red[1][tid][3];
    const int rep = (blockIdx.x & 31) * Ntot;   // replica row: kills hot-line atomics
    atomicAdd(&osum[rep + nb0 + tid], s);
    atomicAdd(&osq[rep + nb0 + tid], q);
  }
}

// ---------------------------------------------------------------------------
// Replica-reducing finalize: sum/sq are [R][C]; thread c reduces R replicas.
// ---------------------------------------------------------------------------
__global__ void finalize_k(const float* __restrict__ sum, const float* __restrict__ sq,
                           const float* __restrict__ g, const float* __restrict__ b,
                           float* __restrict__ oa, float* __restrict__ ob, int C, int R,
                           float invn) {
  const int c = threadIdx.x;
  if (c < C) {
    float s = 0.f, q = 0.f;
    for (int r = 0; r < R; ++r) { s += sum[r * C + c]; q += sq[r * C + c]; }
    const float m = s * invn;
    const float var = q * invn - m * m;
    const float a = g[c] / sqrtf(var + 1e-5f);
    oa[c] = a;
    ob[c] = b[c] - m * a;
  }
}

// out = leaky(a2*t2+b2) + asc*tsc+bsc   (t2, tsc bf16)
__global__ __launch_bounds__(256) void final_k(float* __restrict__ o,
                                               const __bf16* __restrict__ t2,
                                               const __bf16* __restrict__ tsc,
                                               const float* __restrict__ a2,
                                               const float* __restrict__ b2,
                                               const float* __restrict__ asc,
                                               const float* __restrict__ bsc) {
  const int idx = (blockIdx.x << 8) + threadIdx.x;
  const int c = (idx << 2) & 255;
  const bf4 tv = *(const bf4*)&t2[(size_t)idx << 2];
  const bf4 sv = *(const bf4*)&tsc[(size_t)idx << 2];
  float4 r;
  r.x = lk(a2[c + 0] * bf2f(tv[0]) + b2[c + 0]) + asc[c + 0] * bf2f(sv[0]) + bsc[c + 0];
  r.y = lk(a2[c + 1] * bf2f(tv[1]) + b2[c + 1]) + asc[c + 1] * bf2f(sv[1]) + bsc[c + 1];
  r.z = lk(a2[c + 2] * bf2f(tv[2]) + b2[c + 2]) + asc[c + 2] * bf2f(sv[2]) + bsc[c + 2];
  r.w = lk(a2[c + 3] * bf2f(tv[3]) + b2[c + 3]) + asc[c + 3] * bf2f(sv[3]) + bsc[c + 3];
  ((float4*)o)[idx] = r;
}

// ---------------------------------------------------------------------------
// Edge activity test: true iff any kernel point has nonzero influence.
// ---------------------------------------------------------------------------
__device__ __forceinline__ bool edge_active(const float* __restrict__ pos,
                                            const float* __restrict__ kp,
                                            int ref, int q) {
  const float4 pr = *(const float4*)&pos[ref * 4];
  const float4 pq = *(const float4*)&pos[q * 4];
  const float rx = pr.y - pq.y, ry = pr.z - pq.z, rz = pr.w - pq.w;
  bool act = false;
#pragma unroll
  for (int k = 0; k < NK; ++k) {
    const float dx = rx - kp[k * 3 + 0];
    const float dy = ry - kp[k * 3 + 1];
    const float dz = rz - kp[k * 3 + 2];
    act = act || (dx * dx + dy * dy + dz * dz < SIGK * SIGK);
  }
  return act;
}

// ---------------------------------------------------------------------------
// Counting sort of ACTIVE edges by e_query (flags decided once in hist).
// ---------------------------------------------------------------------------
__global__ __launch_bounds__(256) void hist_k(const int* __restrict__ er,
                                              const int* __restrict__ eq,
                                              const float* __restrict__ pos,
                                              const float* __restrict__ kp,
                                              int* __restrict__ cnt,
                                              unsigned char* __restrict__ flags) {
  const int stride = gridDim.x << 8;
  for (int e = (blockIdx.x << 8) + threadIdx.x; e < EDG; e += stride) {
    const int q = eq[e];
    const bool act = edge_active(pos, kp, er[e], q);
    flags[e] = act ? 1 : 0;
    if (act) atomicAdd(&cnt[q], 1);
  }
}

__global__ __launch_bounds__(256) void scanA_k(const int* __restrict__ cnt, int* __restrict__ part) {
  __shared__ int s[256];
  const int tid = threadIdx.x;
  const int base = blockIdx.x * SCH;
  int acc = 0;
  for (int i = tid; i < SCH; i += 256) {
    const int idx = base + i;
    if (idx < NP) acc += cnt[idx];
  }
  s[tid] = acc;
  __syncthreads();
  for (int d = 128; d > 0; d >>= 1) {
    if (tid < d) s[tid] += s[tid + d];
    __syncthreads();
  }
  if (tid == 0) part[blockIdx.x] = s[0];
}

__global__ void scanB_k(int* __restrict__ part, int* __restrict__ off) {
  if (threadIdx.x == 0) {
    int run = 0;
    for (int i = 0; i < SNB; ++i) { const int v = part[i]; part[i] = run; run += v; }
    off[NP] = run;              // total ACTIVE edges
  }
}

__global__ __launch_bounds__(256) void scanC_k(const int* __restrict__ cnt,
                                               const int* __restrict__ part,
                                               int* __restrict__ off, int* __restrict__ cur) {
  __shared__ int s[256];
  const int tid = threadIdx.x;
  const int base = blockIdx.x * SCH + tid * 8;
  int loc[8];
  int mysum = 0;
#pragma unroll
  for (int j = 0; j < 8; ++j) {
    const int idx = base + j;
    const int v = (idx < NP) ? cnt[idx] : 0;
    loc[j] = mysum;
    mysum += v;
  }
  s[tid] = mysum;
  __syncthreads();
  for (int d = 1; d < 256; d <<= 1) {
    int v = (tid >= d) ? s[tid - d] : 0;
    __syncthreads();
    s[tid] += v;
    __syncthreads();
  }
  const int tb = part[blockIdx.x] + s[tid] - mysum;
#pragma unroll
  for (int j = 0; j < 8; ++j) {
    const int idx = base + j;
    if (idx < NP) { off[idx] = tb + loc[j]; cur[idx] = tb + loc[j]; }
  }
}

__global__ __launch_bounds__(256) void scat_k(const int* __restrict__ er,
                                              const int* __restrict__ eq,
                                              const unsigned char* __restrict__ flags,
                                              int* __restrict__ cur, int* __restrict__ sref) {
  const int stride = gridDim.x << 8;
  for (int e = (blockIdx.x << 8) + threadIdx.x; e < EDG; e += stride) {
    if (flags[e]) {
      const int p = atomicAdd(&cur[eq[e]], 1);
      if (p < EDG) sref[p] = er[e];
    }
  }
}

// ---------------------------------------------------------------------------
// One-shot preshuffle of all weights into bf16 MFMA B-frag layouts.
// ---------------------------------------------------------------------------
__device__ __forceinline__ void wshuf1(const float* W, __bf16* Wp, int idx, int Ntot) {
  const int j = idx & 7;
  const int lane = (idx >> 3) & 63;
  const int rest = idx >> 9;
  const int NTG = Ntot >> 4;
  const int ntg = rest % NTG;
  const int ks = rest / NTG;
  Wp[idx] = (__bf16)W[(size_t)(ks * 32 + ((lane >> 4) << 3) + j) * Ntot + ntg * 16 + (lane & 15)];
}

__global__ __launch_bounds__(256) void allshuf_k(const float* __restrict__ W1,
                                                 const float* __restrict__ Wsc,
                                                 const float* __restrict__ W2,
                                                 const float* __restrict__ Wkp,
                                                 __bf16* __restrict__ base) {
  const int i = (blockIdx.x << 8) + threadIdx.x;
  if (i < 8192) {
    wshuf1(W1, base, i, 64);
  } else if (i < 40960) {
    wshuf1(Wsc, base + 8192, i - 8192, 256);
  } else if (i < 57344) {
    wshuf1(W2, base + 40960, i - 40960, 256);
  } else if (i < 118784) {
    const int idx = i - 57344;
    const int j = idx & 7;
    const int lane = (idx >> 3) & 63;
    const int nt = (idx >> 9) & 3;
    const int kb = (idx >> 11) & 1;
    const int k = idx >> 12;
    const int kd = kb * 32 + ((lane >> 4) << 3) + j;
    const int n = nt * 16 + (lane & 15);
    (base + 57344)[idx] = (__bf16)Wkp[(k * 64 + kd) * 64 + n];
  }
}

// ---------------------------------------------------------------------------
// KPConv gather: block = 16 queries (256 thr), pre-filtered active edges.
// r6 PMC: VALUBusy 50% but essential FMA work is ~9us device-wide -> per-edge
// OVERHEAD dominates. This version removes it:
//  - qidxL byte array direct-filled by 16 threads (kills the 5-level
//    LDS-dependent binary search per edge)
//  - 16 query positions preloaded to LDS (was a random gather per edge)
//  - inflF row stride 20 floats: banks repeat mod 8 rows instead of mod 2
//    (r6 bank-conflict 5.06M cycles)
//  - stage 2 unroll 2 (was forced unroll 1)
//  - normleaky FUSED: gather t1b directly, apply leaky(a*v+b) in the loop
//    (a,b = 8 regs per lane) -> whole 25.6MB-traffic kernel deleted.
// Phase B: MFMA y = agg @ Wk; column stats -> 64-replica accumulators.
// ---------------------------------------------------------------------------
__global__ __launch_bounds__(256, 4) void kpagg_k(const float* __restrict__ pos,
                                                  const int* __restrict__ sref,
                                                  const int* __restrict__ off,
                                                  const float* __restrict__ kpts,
                                                  const __bf16* __restrict__ Wf,
                                                  const __bf16* __restrict__ t1b,
                                                  const float* __restrict__ av,
                                                  const float* __restrict__ bv,
                                                  float* __restrict__ y,
                                                  float* __restrict__ osum,
                                                  float* __restrict__ osq) {
  constexpr int INFL_BYTES = MAXE * ISTR * 4;   // 20,480
  constexpr int UNION_BYTES = 16 * AGP * 2;     // 30,976 > 20,480 + 1,024
  __shared__ __align__(16) char uSm[UNION_BYTES];
  __shared__ int qoffL[17];
  __shared__ float kpL[48];
  __shared__ float4 qposL[16];
  __shared__ unsigned char qidxL[MAXE];
  float* inflF = (float*)uSm;                   // [MAXE][ISTR], wk[15]=0 pad
  int* refsL = (int*)(uSm + INFL_BYTES);        // [MAXE]
  __bf16* aggL = (__bf16*)uSm;                  // [16][AGP] (overlays the above)

  const int tid = threadIdx.x;
  const int q0 = blockIdx.x << 4;
  if (tid < 17) qoffL[tid] = off[q0 + tid];
  if (tid >= 32 && tid < 77) kpL[tid - 32] = kpts[tid - 32];
  if (tid >= 80 && tid < 96) qposL[tid - 80] = *(const float4*)&pos[(q0 + tid - 80) * 4];
  __syncthreads();

  const int e0 = qoffL[0];
  int nE = qoffL[16] - e0;
  if (nE > MAXE) nE = MAXE;
  if (nE == 0 && tid == 0) refsL[0] = 0;        // keep stage-2 prologue in-bounds

  // query-index fill (replaces per-edge binary search)
  if (tid < 16) {
    int a = qoffL[tid] - e0, b = qoffL[tid + 1] - e0;
    if (a > nE) a = nE;
    if (b > nE) b = nE;
    for (int i = a; i < b; ++i) qidxL[i] = (unsigned char)tid;
  }
  __syncthreads();

  // ---- stage 1: influence fill (<=1 edge per thread since MAXE == blockDim) ----
  if (tid < nE) {
    const int i = tid;
    const int ref = sref[e0 + i];
    refsL[i] = ref;
    const float4 pr = *(const float4*)&pos[ref * 4];
    const float4 pq = qposL[qidxL[i]];
    const float rx = pr.y - pq.y, ry = pr.z - pq.z, rz = pr.w - pq.w;
    float wk[16];
#pragma unroll
    for (int k = 0; k < NK; ++k) {
      const float dx = rx - kpL[k * 3 + 0];
      const float dy = ry - kpL[k * 3 + 1];
      const float dz = rz - kpL[k * 3 + 2];
      const float w = 1.f - sqrtf(dx * dx + dy * dy + dz * dz) * (1.f / SIGK);
      wk[k] = w > 0.f ? w : 0.f;
    }
    wk[15] = 0.f;
    *(float4*)&inflF[i * ISTR + 0]  = make_float4(wk[0], wk[1], wk[2], wk[3]);
    *(float4*)&inflF[i * ISTR + 4]  = make_float4(wk[4], wk[5], wk[6], wk[7]);
    *(float4*)&inflF[i * ISTR + 8]  = make_float4(wk[8], wk[9], wk[10], wk[11]);
    *(float4*)&inflF[i * ISTR + 12] = make_float4(wk[12], wk[13], wk[14], wk[15]);
  }
  __syncthreads();

  // ---- stage 2: register accumulation (t1b gather + fused affine+leaky) ----
  const int wv = tid >> 6, lane = tid & 63;
  const int ql = (wv << 2) + (lane >> 4);   // query owned by this lane
  const int t4 = (lane & 15) << 2;          // channel chunk
  const int le0 = qoffL[ql] - e0;
  int le1 = qoffL[ql + 1] - e0;
  if (le1 > nE) le1 = nE;
  const int len = le1 - le0;

  const float4 aV = *(const float4*)&av[t4];
  const float4 bV = *(const float4*)&bv[t4];

  float acc[NK][4];
#pragma unroll
  for (int k = 0; k < NK; ++k) { acc[k][0] = acc[k][1] = acc[k][2] = acc[k][3] = 0.f; }

  // 2-deep h prefetch; ref index read one more iteration ahead.
  const int j0 = (len > 0) ? le0 : 0;
  const int j1 = (len > 1) ? le0 + 1 : j0;
  const int j2 = (len > 2) ? le0 + 2 : j1;
  bf4 hA = *(const bf4*)&t1b[(size_t)refsL[j0] * 64 + t4];
  bf4 hB = *(const bf4*)&t1b[(size_t)refsL[j1] * 64 + t4];
  int refC = refsL[j2];
#pragma unroll 2
  for (int j = le0; j < le1; ++j) {
    const bf4 hv = hA;
    hA = hB;
    hB = *(const bf4*)&t1b[(size_t)refC * 64 + t4];   // prefetch j+2
    const int jn = (j + 3 < le1) ? j + 3 : le1 - 1;
    refC = refsL[jn];                                  // ref for j+3
    const float f0 = lk(aV.x * bf2f(hv[0]) + bV.x);
    const float f1 = lk(aV.y * bf2f(hv[1]) + bV.y);
    const float f2 = lk(aV.z * bf2f(hv[2]) + bV.z);
    const float f3 = lk(aV.w * bf2f(hv[3]) + bV.w);
    const float4 wA = *(const float4*)&inflF[j * ISTR + 0];
    const float4 wB = *(const float4*)&inflF[j * ISTR + 4];
    const float4 wC = *(const float4*)&inflF[j * ISTR + 8];
    const float4 wD = *(const float4*)&inflF[j * ISTR + 12];
    const float wk[NK] = {wA.x, wA.y, wA.z, wA.w, wB.x, wB.y, wB.z, wB.w,
                          wC.x, wC.y, wC.z, wC.w, wD.x, wD.y, wD.z};
#pragma unroll
    for (int k = 0; k < NK; ++k) {
      acc[k][0] += wk[k] * f0;
      acc[k][1] += wk[k] * f1;
      acc[k][2] += wk[k] * f2;
      acc[k][3] += wk[k] * f3;
    }
  }

  // inflF/refsL fully consumed by every wave before aggL overwrites the union
  __syncthreads();

  // write agg (bf16) for phase B
#pragma unroll
  for (int k = 0; k < NK; ++k) {
    bf4 o;
    o[0] = (__bf16)acc[k][0]; o[1] = (__bf16)acc[k][1];
    o[2] = (__bf16)acc[k][2]; o[3] = (__bf16)acc[k][3];
    *(bf4*)&aggL[ql * AGP + k * 64 + t4] = o;
  }
  __syncthreads();

  // ---- phase B: MFMA y = agg @ Wk, wave wv -> cols [wv*16, wv*16+16) ----
  const int m = lane & 15, quad = lane >> 4;
  v4f yacc = {0.f, 0.f, 0.f, 0.f};
  const v8bf* Wf8 = (const v8bf*)Wf;
#pragma unroll
  for (int k = 0; k < NK; ++k)
#pragma unroll
    for (int kb = 0; kb < 2; ++kb) {
      const v8bf av2 = *(const v8bf*)&aggL[m * AGP + k * 64 + kb * 32 + (quad << 3)];
      const v8bf bv2 = Wf8[((k * 2 + kb) * 4 + wv) * 64 + lane];
      yacc = __builtin_amdgcn_mfma_f32_16x16x32_bf16(av2, bv2, yacc, 0, 0, 0);
    }

  float s = 0.f, q2 = 0.f;
#pragma unroll
  for (int r = 0; r < 4; ++r) {
    const float v = yacc[r];
    y[(size_t)(q0 + (quad << 2) + r) * 64 + (wv << 4) + m] = v;
    s += v; q2 += v * v;
  }
  s += __shfl_down(s, 32); s += __shfl_down(s, 16);
  q2 += __shfl_down(q2, 32); q2 += __shfl_down(q2, 16);
  if (quad == 0) {
    const int rep = (blockIdx.x & 63) << 6;   // replica row: kills hot-line atomics
    atomicAdd(&osum[rep + (wv << 4) + m], s);
    atomicAdd(&osq[rep + (wv << 4) + m], q2);
  }
}

// ---------------------------------------------------------------------------
extern "C" void kernel_launch(void* const* d_in, const int* in_sizes, int n_in,
                              void* d_out, int out_size, void* d_ws, size_t ws_size,
                              hipStream_t stream) {
  const float* pos = (const float*)d_in[0];
  const float* x   = (const float*)d_in[1];
  const int* er    = (const int*)d_in[2];
  const int* eq    = (const int*)d_in[3];
  const float* W1  = (const float*)d_in[4];
  const float* g1  = (const float*)d_in[5];
  const float* b1  = (const float*)d_in[6];
  const float* kp  = (const float*)d_in[7];
  const float* Wkp = (const float*)d_in[8];
  const float* gkp = (const float*)d_in[9];
  const float* bkp = (const float*)d_in[10];
  const float* W2  = (const float*)d_in[11];
  const float* g2  = (const float*)d_in[12];
  const float* b2  = (const float*)d_in[13];
  const float* Wsc = (const float*)d_in[14];
  const float* gsc = (const float*)d_in[15];
  const float* bsc = (const float*)d_in[16];
  float* out = (float*)d_out;
  float* ws = (float*)d_ws;

  // stats / affine scratch (replicated accumulators), first 49152 floats
  float* sum1 = ws;              // [32][64]
  float* sq1  = ws + 2048;       // [32][64]
  float* sumsc = ws + 4096;      // [32][256]
  float* sqsc  = ws + 12288;     // [32][256]
  float* sumy = ws + 20480;      // [64][64]
  float* sqy  = ws + 24576;      // [64][64]
  float* sum2 = ws + 28672;      // [32][256]
  float* sq2  = ws + 36864;      // [32][256]
  float* a1v = ws + 45056;   float* b1v  = ws + 45120;
  float* ascv = ws + 45184;  float* bscv = ws + 45440;
  float* ayv = ws + 45696;   float* byv  = ws + 45760;
  float* a2v = ws + 45824;   float* b2v  = ws + 46080;

  // layout (float offsets)
  __bf16* Wpb = (__bf16*)(ws + 49152);           // preshuffled weights
  __bf16* W1p = Wpb;
  __bf16* Wscp = Wpb + 8192;
  __bf16* W2p = Wpb + 40960;
  __bf16* Wfp = Wpb + 57344;
  float* ybuf = ws + 114688 + 3200000;           // fp32 [N*64] (hb slot retired)
  float* t1bf = ybuf + 6400000;                  // bf16 t1 [N*64] region
  __bf16* t1b = (__bf16*)t1bf;
  __bf16* tscb = (__bf16*)ybuf;                  // bf16 [N*256] overlays ybuf+t1b
  int* cnt = (int*)(t1bf + 6400000);             // sort region
  int* off = cnt + 100352;
  int* cur = off + 100352;
  int* part = cur + 100352;
  int* sref = part + 256;
  unsigned char* flags = (unsigned char*)(sref + EDG);   // [EDG] activity flags
  __bf16* t2b = (__bf16*)cnt;                    // bf16 [N*256] overlays sort region

  const float invn = 1.f / (float)NP;

  (void)hipMemsetAsync(ws, 0, 49152 * sizeof(float), stream);
  (void)hipMemsetAsync(cnt, 0, 100352 * sizeof(int), stream);

  // weight preshuffle
  allshuf_k<<<464, 256, 0, stream>>>(W1, Wsc, W2, Wkp, Wpb);

  // unary_1: t1b = bf16(x@W1) (stats fused); fold. (normleaky fused into kpagg)
  mgemm_k<128, 64, false, true><<<dim3(782, 1), 256, 0, stream>>>(
      x, W1p, t1b, NP, 64, nullptr, nullptr, sum1, sq1);
  finalize_k<<<1, 256, 0, stream>>>(sum1, sq1, g1, b1, a1v, b1v, 64, 32, invn);

  // edge sort by query, ACTIVE edges only (flags decided once in hist)
  hist_k<<<2048, 256, 0, stream>>>(er, eq, pos, kp, cnt, flags);
  scanA_k<<<SNB, 256, 0, stream>>>(cnt, part);
  scanB_k<<<1, 64, 0, stream>>>(part, off);
  scanC_k<<<SNB, 256, 0, stream>>>(cnt, part, off, cur);
  scat_k<<<2048, 256, 0, stream>>>(er, eq, flags, cur, sref);

  // KPConv (y stats fused, 64 replicas; h = leaky(a1*t1+b1) applied inline)
  kpagg_k<<<6250, 256, 0, stream>>>(pos, sref, off, kp, Wfp, t1b, a1v, b1v,
                                    ybuf, sumy, sqy);
  finalize_k<<<1, 256, 0, stream>>>(sumy, sqy, gkp, bkp, ayv, byv, 64, 64, invn);

  // unary_2: t2b = bf16( leaky(BN(y)) @ W2 ), stats fused (overwrites sort bufs)
  mgemm_k<64, 128, true, true><<<dim3(782, 2), 256, 0, stream>>>(
      ybuf, W2p, t2b, NP, 256, ayv, byv, sum2, sq2);
  finalize_k<<<1, 256, 0, stream>>>(sum2, sq2, g2, b2, a2v, b2v, 256, 32, invn);

  // shortcut: tscb = bf16( x@Wsc ), stats fused (overwrites ybuf/t1b)
  mgemm_k<128, 128, false, true><<<dim3(782, 2), 256, 0, stream>>>(
      x, Wscp, tscb, NP, 256, nullptr, nullptr, sumsc, sqsc);
  finalize_k<<<1, 256, 0, stream>>>(sumsc, sqsc, gsc, bsc, ascv, bscv, 256, 32, invn);

  // out = leaky(BN(t2)) + BN(tsc)
  final_k<<<25000, 256, 0, stream>>>(out, t2b, tscb, a2v, b2v, ascv, bscv);
}